// Round 6
// baseline (58.756 us; speedup 1.0000x reference)
//
#include <hip/hip_runtime.h>
#include <hip/hip_bf16.h>

#define HIDDEN 128
#define NHEAD  8
#define DHEAD  16
#define KBLK   64
#define QBLK   64     // 64 q-rows per ONE-WAVE block (4 sub-blocks of 16)
#define CHUNK  512    // split-K chunk (multiple of KBLK)
#define TILEB  6144   // per-(b,h,keytile): khi 2K | klo 2K | vT 2K
#define QSCALE 5.77078016355585277626f   // sqrt(d_head)*log2(e): softmax in log2 domain

typedef __attribute__((ext_vector_type(8))) __bf16 bf16x8;
typedef __attribute__((ext_vector_type(4))) __bf16 bf16x4;
typedef __attribute__((ext_vector_type(4))) float  f32x4;
typedef __attribute__((ext_vector_type(2))) float  f32x2;

// ds_read_b64_tr_b16 (prepass only)
#define TR_READ(dst, addr, imm) \
    asm volatile("ds_read_b64_tr_b16 %0, %1 offset:" imm : "=v"(dst) : "v"(addr) : "memory")

// async global->LDS, 16B/lane, linear dest
#define GL16(gsrc, ldsoff) \
    __builtin_amdgcn_global_load_lds((const __attribute__((address_space(1))) unsigned int*)(gsrc), \
        (__attribute__((address_space(3))) unsigned int*)(unsigned)(ldsoff), 16, 0, 0)

__device__ __forceinline__ int permrow(int k) {
    return (k & 3) | (((k >> 3) & 3) << 2) | (((k >> 2) & 1) << 4) | ((k >> 5) << 5);
}

// Key permutation: key k stored at QK-A-tile (sub, irow) so that the QK C-output
// value s[sub][r] in lane (g,lr) is exactly PV-A-operand slot (g*8 + sub*4 + r).
//   k = 32*(sub>>1) + (irow>>2)*8 + (sub&1)*4 + (irow&3)
__device__ __forceinline__ int ksub(int k)  { return ((k >> 5) << 1) | ((k >> 2) & 1); }
__device__ __forceinline__ int kirow(int k) { return (((k >> 3) & 3) << 2) | (k & 3); }

// ---------------------------------------------------------------------------
// Pre-pass: pack KV into MFMA-ready per-(b,h,tile) 6KB blocks.
//   [0,2048):    K_hi  [sub4][half2(dims0-7|8-15)][row16][16B], rows = kirow(k)
//   [2048,4096): K_lo  same
//   [4096,6144): V^T   rows d=0..15 x 128B, 16B groups XOR-swizzled by ((d&7)<<4)
// ---------------------------------------------------------------------------
__global__ __launch_bounds__(256, 4)
void mha_prepass(const float* __restrict__ kv, char* __restrict__ kbuf, int S)
{
    const int t    = blockIdx.x;
    const int b    = blockIdx.y;
    const int zh   = blockIdx.z;
    const int lane = threadIdx.x & 63;
    const int wave = threadIdx.x >> 6;
    const int h    = zh * 4 + wave;
    const int k    = lane;

    __shared__ __align__(16) __bf16 Vw[4][64][16];

    const float* kp = kv + ((size_t)(b * S + t * KBLK + k) * (2 * HIDDEN)) + h * DHEAD;
    char* tb = kbuf + (((size_t)(b * NHEAD + h) * (S / KBLK)) + t) * TILEB;

    // ---- K hi/lo, permuted row placement ----
    f32x4 k0 = *(const f32x4*)(kp + 0);
    f32x4 k1 = *(const f32x4*)(kp + 4);
    f32x4 k2 = *(const f32x4*)(kp + 8);
    f32x4 k3 = *(const f32x4*)(kp + 12);
    bf16x8 hiA, hiB, loA, loB;
    #pragma unroll
    for (int i = 0; i < 4; ++i) {
        __bf16 h0 = (__bf16)k0[i]; hiA[i]     = h0; loA[i]     = (__bf16)(k0[i] - (float)h0);
        __bf16 h1 = (__bf16)k1[i]; hiA[i + 4] = h1; loA[i + 4] = (__bf16)(k1[i] - (float)h1);
        __bf16 h2 = (__bf16)k2[i]; hiB[i]     = h2; loB[i]     = (__bf16)(k2[i] - (float)h2);
        __bf16 h3 = (__bf16)k3[i]; hiB[i + 4] = h3; loB[i + 4] = (__bf16)(k3[i] - (float)h3);
    }
    const int ka = ksub(k) * 512 + kirow(k) * 16;
    *(bf16x8*)(tb + ka)              = hiA;
    *(bf16x8*)(tb + ka + 256)        = hiB;
    *(bf16x8*)(tb + 2048 + ka)       = loA;
    *(bf16x8*)(tb + 2048 + ka + 256) = loB;

    // ---- V -> V^T via perm rows + tr_read; swizzled natural-slot store ----
    const float* vp = kp + HIDDEN;
    f32x4 v0 = *(const f32x4*)(vp + 0);
    f32x4 v1 = *(const f32x4*)(vp + 4);
    f32x4 v2 = *(const f32x4*)(vp + 8);
    f32x4 v3 = *(const f32x4*)(vp + 12);
    bf16x8 va, vb;
    #pragma unroll
    for (int i = 0; i < 4; ++i) {
        va[i] = (__bf16)v0[i]; va[i + 4] = (__bf16)v1[i];
        vb[i] = (__bf16)v2[i]; vb[i + 4] = (__bf16)v3[i];
    }
    const int pr = permrow(k);
    *(bf16x8*)&Vw[wave][pr][0] = va;
    *(bf16x8*)&Vw[wave][pr][8] = vb;

    const unsigned vbase = (unsigned)(unsigned long long)(const void*)&Vw[wave][0][0] + lane * 8;
    bf16x4 t0v, t1v, t2v, t3v;
    TR_READ(t0v, vbase, "0");
    TR_READ(t1v, vbase, "512");
    TR_READ(t2v, vbase, "1024");
    TR_READ(t3v, vbase, "1536");
    asm volatile("s_waitcnt lgkmcnt(0)" ::: "memory");
    __builtin_amdgcn_sched_barrier(0);
    bf16x8 w0, w1;
    #pragma unroll
    for (int i = 0; i < 4; ++i) {
        w0[i] = t0v[i]; w0[i + 4] = t1v[i];
        w1[i] = t2v[i]; w1[i + 4] = t3v[i];
    }
    const int lr = lane & 15, g = lane >> 4, sw = (lr & 7) << 4;
    char* vt = tb + 4096 + lr * 128;
    *(bf16x8*)(vt + ((g * 16) ^ sw))        = w0;   // V^T[d=lr][keys g*8..+7]
    *(bf16x8*)(vt + ((64 + g * 16) ^ sw))   = w1;   // keys 32+g*8..+7
}

// ---------------------------------------------------------------------------
__device__ __forceinline__ void stage_pre(const char* tile, unsigned ldsoff, int lane)
{
    const char* gp = tile + lane * 16;
    #pragma unroll
    for (int sg = 0; sg < 6; ++sg)
        GL16(gp + sg * 1024, ldsoff + sg * 1024);
}

// fallback staging (no prepass buffer): 1 wave, thread = key
__device__ __forceinline__ void stage_raw(const float* kv, int b, int S, int h, int kb,
                                          char* Sb, int lane)
{
    const int k = lane;
    const float* kp = kv + ((size_t)(b * S + kb + k) * (2 * HIDDEN)) + h * DHEAD;
    f32x4 k0 = *(const f32x4*)(kp + 0);
    f32x4 k1 = *(const f32x4*)(kp + 4);
    f32x4 k2 = *(const f32x4*)(kp + 8);
    f32x4 k3 = *(const f32x4*)(kp + 12);
    bf16x8 hiA, hiB, loA, loB;
    #pragma unroll
    for (int i = 0; i < 4; ++i) {
        __bf16 h0 = (__bf16)k0[i]; hiA[i]     = h0; loA[i]     = (__bf16)(k0[i] - (float)h0);
        __bf16 h1 = (__bf16)k1[i]; hiA[i + 4] = h1; loA[i + 4] = (__bf16)(k1[i] - (float)h1);
        __bf16 h2 = (__bf16)k2[i]; hiB[i]     = h2; loB[i]     = (__bf16)(k2[i] - (float)h2);
        __bf16 h3 = (__bf16)k3[i]; hiB[i + 4] = h3; loB[i + 4] = (__bf16)(k3[i] - (float)h3);
    }
    const int ka = ksub(k) * 512 + kirow(k) * 16;
    *(bf16x8*)(Sb + ka)              = hiA;
    *(bf16x8*)(Sb + ka + 256)        = hiB;
    *(bf16x8*)(Sb + 2048 + ka)       = loA;
    *(bf16x8*)(Sb + 2048 + ka + 256) = loB;
    const float* vp = kp + HIDDEN;
    f32x4 v0 = *(const f32x4*)(vp + 0);
    f32x4 v1 = *(const f32x4*)(vp + 4);
    f32x4 v2 = *(const f32x4*)(vp + 8);
    f32x4 v3 = *(const f32x4*)(vp + 12);
    float vf[16];
    #pragma unroll
    for (int i = 0; i < 4; ++i) { vf[i] = v0[i]; vf[4+i] = v1[i]; vf[8+i] = v2[i]; vf[12+i] = v3[i]; }
    const int kgrp = (k >> 3) * 16, koff = (k & 7) * 2;
    #pragma unroll
    for (int d = 0; d < 16; ++d) {
        const int addr = 4096 + d * 128 + (kgrp ^ ((d & 7) << 4)) + koff;
        *(__bf16*)(Sb + addr) = (__bf16)vf[d];
    }
}

template<bool SPLIT, bool PRE>
__global__ __launch_bounds__(64, 3)
void mha_fwd(const float* __restrict__ kv,
             const float* __restrict__ q,
             const int*   __restrict__ seq_len,
             const char*  __restrict__ kbuf,
             float* __restrict__ out,
             float* __restrict__ pbuf,
             float* __restrict__ mlbuf,
             int S, int nc)
{
    const int qtile = blockIdx.x;
    const int h     = blockIdx.y;
    int b, c0;
    if (SPLIT) { b = blockIdx.z / nc; c0 = blockIdx.z % nc; }
    else       { b = blockIdx.z;      c0 = 0; }
    const int L = seq_len[b];
    const int kstart = SPLIT ? c0 * CHUNK : 0;
    if (SPLIT && kstart >= L) return;
    const int kend = SPLIT ? min(L, kstart + CHUNK) : L;

    const int lane = threadIdx.x;      // 64 threads = 1 wave
    const int g    = lane >> 4;
    const int lr   = lane & 15;
    const int sw   = (lr & 7) << 4;

    __shared__ __align__(16) char Stg[2][TILEB];

    // ---- Q fragments, 4 q-blocks of 16 rows; slots 0-15 = Q_hi, 16-31 = Q_lo ----
    const int qbase = qtile * QBLK;
    bf16x8 qf[4];
    #pragma unroll
    for (int qb = 0; qb < 4; ++qb) {
        const float* qp = q + ((size_t)(b * S + qbase + qb * 16 + lr) * HIDDEN) + h * DHEAD + (g & 1) * 8;
        #pragma unroll
        for (int j = 0; j < 8; ++j) {
            float qv = qp[j] * QSCALE;
            __bf16 hi = (__bf16)qv;
            qf[qb][j] = (g < 2) ? hi : (__bf16)(qv - (float)hi);
        }
    }
    asm volatile("s_waitcnt vmcnt(0)" ::: "memory");   // clean vmcnt before staging

    const unsigned stg0 = (unsigned)(unsigned long long)(const void*)&Stg[0][0];
    const char* tcur = PRE ? kbuf + (((size_t)(b * NHEAD + h) * (S / KBLK)) + (kstart >> 6)) * TILEB
                           : nullptr;

    f32x4 acc[4];
    float m[4], lsum[4];
    #pragma unroll
    for (int qb = 0; qb < 4; ++qb) {
        acc[qb] = (f32x4){0.f, 0.f, 0.f, 0.f};
        m[qb] = -1e30f; lsum[qb] = 0.f;
    }

    const int ntiles = (kend - kstart + KBLK - 1) >> 6;
    if constexpr (PRE) stage_pre(tcur, stg0, lane);

    for (int ti = 0; ti < ntiles; ++ti) {
        const int kb = kstart + ti * KBLK;
        const char* Sb;
        if constexpr (PRE) {
            Sb = &Stg[ti & 1][0];
            if (ti + 1 < ntiles) {
                stage_pre(tcur + TILEB, stg0 + (unsigned)(((ti & 1) ^ 1) * TILEB), lane);
                asm volatile("s_waitcnt vmcnt(6)" ::: "memory");
            } else {
                asm volatile("s_waitcnt vmcnt(0)" ::: "memory");
            }
            __builtin_amdgcn_sched_barrier(0);
        } else {
            Sb = &Stg[0][0];
            stage_raw(kv, b, S, h, kb, (char*)Sb, lane);
            asm volatile("s_waitcnt lgkmcnt(0)" ::: "memory");
            __builtin_amdgcn_sched_barrier(0);
        }

        // ---- K/V fragments: read ONCE, reused by all 4 q-blocks ----
        bf16x8 kfh[4], kfl[4];
        #pragma unroll
        for (int sub = 0; sub < 4; ++sub) {
            kfh[sub] = *(const bf16x8*)(Sb + sub * 512 + (g & 1) * 256 + lr * 16);
            kfl[sub] = *(const bf16x8*)(Sb + 2048 + sub * 512 + (g & 1) * 256 + lr * 16);
        }
        bf16x8 vb0 = *(const bf16x8*)(Sb + 4096 + lr * 128 + ((g * 16) ^ sw));
        bf16x8 vb1 = *(const bf16x8*)(Sb + 4096 + lr * 128 + ((64 + g * 16) ^ sw));

        const bool bnd = (kb + KBLK > kend);

        #pragma unroll
        for (int qb = 0; qb < 4; ++qb) {
            // QK^T swapped+permuted: s[sub][r] = S[q=qb*16+lr][key = kb + pi(sub,g,r)]
            f32x4 s[4];
            #pragma unroll
            for (int sub = 0; sub < 4; ++sub) {
                f32x4 z = {0.f, 0.f, 0.f, 0.f};
                z = __builtin_amdgcn_mfma_f32_16x16x32_bf16(kfh[sub], qf[qb], z, 0, 0, 0);
                s[sub] = __builtin_amdgcn_mfma_f32_16x16x32_bf16(kfl[sub], qf[qb], z, 0, 0, 0);
            }
            if (bnd) {
                #pragma unroll
                for (int sub = 0; sub < 4; ++sub) {
                    const int kb2 = kb + (sub >> 1) * 32 + (sub & 1) * 4 + g * 8;
                    #pragma unroll
                    for (int r = 0; r < 4; ++r)
                        if (kb2 + r >= kend) s[sub][r] = -1e30f;
                }
            }

            // ---- row max: 15 in-lane + 2 shfl ----
            float t0 = fmaxf(fmaxf(s[0][0], s[0][1]), fmaxf(s[0][2], s[0][3]));
            float t1 = fmaxf(fmaxf(s[1][0], s[1][1]), fmaxf(s[1][2], s[1][3]));
            float t2 = fmaxf(fmaxf(s[2][0], s[2][1]), fmaxf(s[2][2], s[2][3]));
            float t3 = fmaxf(fmaxf(s[3][0], s[3][1]), fmaxf(s[3][2], s[3][3]));
            float tmax = fmaxf(fmaxf(t0, t1), fmaxf(t2, t3));
            tmax = fmaxf(tmax, __shfl_xor(tmax, 16));
            tmax = fmaxf(tmax, __shfl_xor(tmax, 32));

            const float mn = fmaxf(m[qb], tmax);
            const float alpha = exp2f(m[qb] - mn);
            m[qb] = mn;

            // ---- P: pure in-lane exp2 + pack (no LDS round-trip) ----
            float rsum = 0.f;
            bf16x8 pa0, pa1;
            #pragma unroll
            for (int sub = 0; sub < 2; ++sub)
                #pragma unroll
                for (int r = 0; r < 4; ++r) {
                    float p = exp2f(s[sub][r] - mn);
                    rsum += p;
                    pa0[sub * 4 + r] = (__bf16)p;
                }
            #pragma unroll
            for (int sub = 2; sub < 4; ++sub)
                #pragma unroll
                for (int r = 0; r < 4; ++r) {
                    float p = exp2f(s[sub][r] - mn);
                    rsum += p;
                    pa1[(sub - 2) * 4 + r] = (__bf16)p;
                }
            rsum += __shfl_xor(rsum, 16);
            rsum += __shfl_xor(rsum, 32);
            lsum[qb] = lsum[qb] * alpha + rsum;
            acc[qb] *= alpha;

            // ---- PV swapped: O^T = V^T * P^T ----
            acc[qb] = __builtin_amdgcn_mfma_f32_16x16x32_bf16(vb0, pa0, acc[qb], 0, 0, 0);
            acc[qb] = __builtin_amdgcn_mfma_f32_16x16x32_bf16(vb1, pa1, acc[qb], 0, 0, 0);
        }
        if constexpr (PRE) tcur += TILEB;
    }

    // ---- epilogue (m, lsum in base-2 units) ----
    #pragma unroll
    for (int qb = 0; qb < 4; ++qb) {
        const int qglob = qbase + qb * 16 + lr;
        if (SPLIT) {
            const size_t row = (((size_t)b * nc + c0) * S + qglob) * NHEAD + h;
            *(f32x4*)&pbuf[row * DHEAD + g * 4] = acc[qb];
            if (g == 0) { f32x2 ml = {m[qb], lsum[qb]}; *(f32x2*)&mlbuf[row * 2] = ml; }
        } else {
            const float inv = 1.0f / lsum[qb];
            *(f32x4*)&out[((size_t)b * S + qglob) * HIDDEN + h * DHEAD + g * 4] = acc[qb] * inv;
        }
    }
}

__global__ __launch_bounds__(256)
void mha_merge(const float* __restrict__ pbuf, const float* __restrict__ mlbuf,
               const int* __restrict__ seq_len, float* __restrict__ out, int S, int nc)
{
    const int t = blockIdx.x * 256 + threadIdx.x;   // (b, q, h), h fastest
    const int h = t & (NHEAD - 1);
    const int rest = t >> 3;
    const int qg = rest % S;
    const int b  = rest / S;
    const int L  = seq_len[b];
    const int nch = (L + CHUNK - 1) / CHUNK;

    const size_t cstr = (size_t)S * NHEAD;
    const size_t row0 = ((size_t)b * nc) * cstr + (size_t)qg * NHEAD + h;

    float mv[8], lv[8];
    float M = -1e30f;
    for (int c = 0; c < nch; ++c) {
        f32x2 ml = *(const f32x2*)&mlbuf[(row0 + c * cstr) * 2];
        mv[c] = ml[0]; lv[c] = ml[1];
        M = fmaxf(M, ml[0]);
    }
    float den = 0.f;
    f32x4 o0 = {0,0,0,0}, o1 = o0, o2 = o0, o3 = o0;
    for (int c = 0; c < nch; ++c) {
        float w = exp2f(mv[c] - M);                 // base-2 m
        den += w * lv[c];
        const float* pp = &pbuf[(row0 + c * cstr) * DHEAD];
        o0 += w * *(const f32x4*)&pp[0];
        o1 += w * *(const f32x4*)&pp[4];
        o2 += w * *(const f32x4*)&pp[8];
        o3 += w * *(const f32x4*)&pp[12];
    }
    const float inv = 1.0f / den;
    float* op = &out[((size_t)b * S + qg) * HIDDEN + h * DHEAD];
    *(f32x4*)&op[0]  = o0 * inv;
    *(f32x4*)&op[4]  = o1 * inv;
    *(f32x4*)&op[8]  = o2 * inv;
    *(f32x4*)&op[12] = o3 * inv;
}

extern "C" void kernel_launch(void* const* d_in, const int* in_sizes, int n_in,
                              void* d_out, int out_size, void* d_ws, size_t ws_size,
                              hipStream_t stream)
{
    const float* kv      = (const float*)d_in[0];
    const float* query   = (const float*)d_in[1];
    const int*   seq_len = (const int*)d_in[2];
    float* out           = (float*)d_out;

    const int B = in_sizes[2];
    const int S = in_sizes[1] / (B * HIDDEN);
    const int nc = (S + CHUNK - 1) / CHUNK;

    const size_t preb = (size_t)B * NHEAD * (S / KBLK) * TILEB;
    const size_t pb   = (size_t)B * nc * S * NHEAD * DHEAD * sizeof(float);
    const size_t mlb  = (size_t)B * nc * S * NHEAD * 2 * sizeof(float);

    if (nc <= 8 && ws_size >= preb + pb + mlb) {
        char*  kbuf  = (char*)d_ws;
        float* pbuf  = (float*)((char*)d_ws + preb);
        float* mlbuf = (float*)((char*)d_ws + preb + pb);
        mha_prepass<<<dim3(S / KBLK, B, 2), dim3(256), 0, stream>>>(kv, kbuf, S);
        mha_fwd<true, true><<<dim3(S / QBLK, NHEAD, B * nc), dim3(64), 0, stream>>>(
            kv, query, seq_len, kbuf, nullptr, pbuf, mlbuf, S, nc);
        const int nrows = B * S * NHEAD;
        mha_merge<<<dim3((nrows + 255) / 256), dim3(256), 0, stream>>>(pbuf, mlbuf, seq_len, out, S, nc);
    } else if (nc <= 8 && ws_size >= pb + mlb) {
        float* pbuf  = (float*)d_ws;
        float* mlbuf = (float*)((char*)d_ws + pb);
        mha_fwd<true, false><<<dim3(S / QBLK, NHEAD, B * nc), dim3(64), 0, stream>>>(
            kv, query, seq_len, nullptr, nullptr, pbuf, mlbuf, S, nc);
        const int nrows = B * S * NHEAD;
        mha_merge<<<dim3((nrows + 255) / 256), dim3(256), 0, stream>>>(pbuf, mlbuf, seq_len, out, S, nc);
    } else if (ws_size >= preb) {
        char* kbuf = (char*)d_ws;
        mha_prepass<<<dim3(S / KBLK, B, 2), dim3(256), 0, stream>>>(kv, kbuf, S);
        mha_fwd<false, true><<<dim3(S / QBLK, NHEAD, B), dim3(64), 0, stream>>>(
            kv, query, seq_len, kbuf, out, nullptr, nullptr, S, 1);
    } else {
        mha_fwd<false, false><<<dim3(S / QBLK, NHEAD, B), dim3(64), 0, stream>>>(
            kv, query, seq_len, nullptr, out, nullptr, nullptr, S, 1);
    }
}

// Round 7
// 45.003 us; speedup vs baseline: 1.3056x; 1.3056x over previous
//
#include <hip/hip_runtime.h>
#include <hip/hip_bf16.h>

#define HIDDEN 128
#define NHEAD  8
#define DHEAD  16
#define KBLK   64
#define QBLK   64     // 4 waves x 16 query rows
#define CHUNK  512    // split-K chunk (multiple of KBLK)
#define TILEB  6144   // staged bytes per keytile: khi 2K | klo 2K | vT 2K
#define QSCALE 5.77078016355585277626f   // sqrt(d_head)*log2(e): softmax in log2 domain

typedef __attribute__((ext_vector_type(8))) __bf16 bf16x8;
typedef __attribute__((ext_vector_type(4))) __bf16 bf16x4;
typedef __attribute__((ext_vector_type(4))) float  f32x4;
typedef __attribute__((ext_vector_type(2))) float  f32x2;
typedef __attribute__((ext_vector_type(4))) int    i32x4;

// Key permutation: key k stored at QK-A-tile (sub, irow) so that the QK C-output
// value s[sub][r] in lane (g,lr) is exactly PV-A-operand slot (g*8 + sub*4 + r).
//   k = 32*(sub>>1) + (irow>>2)*8 + (sub&1)*4 + (irow&3)      [verified r6]
__device__ __forceinline__ int ksub(int k)  { return ((k >> 5) << 1) | ((k >> 2) & 1); }
__device__ __forceinline__ int kirow(int k) { return (((k >> 3) & 3) << 2) | (k & 3); }

// Stg tile layout:
//   [0,2048):    K_hi  [sub4][half2(dims0-7|8-15)][row16][16B], row = kirow(k)
//   [2048,4096): K_lo  same
//   [4096,6144): V^T   rows d=0..15 x 128B, 16B granules XOR-swizzled by ((d&7)<<4)

__device__ __forceinline__ void cvt_store(char* Sb, int ka, i32x4 vaddr,
                                          f32x4 kvec, f32x4 vvec)
{
    bf16x4 khv, klv;
    #pragma unroll
    for (int i = 0; i < 4; ++i) {
        __bf16 hi = (__bf16)kvec[i];
        khv[i] = hi;
        klv[i] = (__bf16)(kvec[i] - (float)hi);
    }
    *(bf16x4*)(Sb + ka)        = khv;
    *(bf16x4*)(Sb + 2048 + ka) = klv;
    #pragma unroll
    for (int i = 0; i < 4; ++i)
        *(__bf16*)(Sb + vaddr[i]) = (__bf16)vvec[i];
}

template<bool SPLIT>
__global__ __launch_bounds__(256, 4)
void mha_fwd(const float* __restrict__ kv,
             const float* __restrict__ q,
             const int*   __restrict__ seq_len,
             float* __restrict__ out,
             float* __restrict__ pbuf,
             float* __restrict__ mlbuf,
             int S, int nc)
{
    const int qtile = blockIdx.x;
    const int h     = blockIdx.y;
    int b, c0;
    if (SPLIT) { b = blockIdx.z / nc; c0 = blockIdx.z % nc; }
    else       { b = blockIdx.z;      c0 = 0; }
    const int L = seq_len[b];
    const int kstart = SPLIT ? c0 * CHUNK : 0;
    if (SPLIT && kstart >= L) return;              // block-uniform exit, before any barrier
    const int kend = SPLIT ? min(L, kstart + CHUNK) : L;

    const int tid  = threadIdx.x;
    const int lane = tid & 63;
    const int wave = tid >> 6;
    const int g    = lane >> 4;
    const int lr   = lane & 15;
    const int sw   = (lr & 7) << 4;

    __shared__ __align__(16) char Stg[2][TILEB];

    // ---- Q fragment (per wave, rows wave*16 + lr): slots 0-15 Q_hi, 16-31 Q_lo ----
    const int qbase = qtile * QBLK + wave * 16;
    bf16x8 qfrag;
    {
        const float* qp = q + ((size_t)(b * S + qbase + lr) * HIDDEN) + h * DHEAD + (g & 1) * 8;
        #pragma unroll
        for (int j = 0; j < 8; ++j) {
            float qv = qp[j] * QSCALE;
            __bf16 hi = (__bf16)qv;
            qfrag[j] = (g < 2) ? hi : (__bf16)(qv - (float)hi);
        }
    }

    // ---- staging assignment: thread = (key sk, dim-quarter qd) ----
    const int sk = tid >> 2;
    const int qd = tid & 3;
    const float* kvp = kv + ((size_t)(b * S + sk) * (2 * HIDDEN)) + h * DHEAD + 4 * qd;
    const int ka = ksub(sk) * 512 + (qd >> 1) * 256 + kirow(sk) * 16 + (qd & 1) * 8;
    i32x4 vaddr;
    #pragma unroll
    for (int i = 0; i < 4; ++i) {
        const int d = 4 * qd + i;
        vaddr[i] = 4096 + d * 128 + (((sk >> 3) * 16) ^ ((d & 7) << 4)) + (sk & 7) * 2;
    }

    f32x4 acc = {0.f, 0.f, 0.f, 0.f};     // acc[r] = O^T[d=g*4+r][q=lr]
    float m = -1e30f, lsum = 0.f;

    const int ntiles = (kend - kstart + KBLK - 1) >> 6;

    // ---- prologue: stage tile 0 ----
    {
        const float* kp = kvp + (size_t)kstart * (2 * HIDDEN);
        f32x4 kvec = *(const f32x4*)kp;
        f32x4 vvec = *(const f32x4*)(kp + HIDDEN);
        cvt_store(&Stg[0][0], ka, vaddr, kvec, vvec);
    }
    __syncthreads();

    for (int ti = 0; ti < ntiles; ++ti) {
        const int kb = kstart + ti * KBLK;
        const char* Sb = &Stg[ti & 1][0];
        const bool hasnext = (ti + 1) < ntiles;

        // ---- T14: issue next tile's global loads BEFORE compute ----
        f32x4 nkv, nvv;
        if (hasnext) {
            const float* kp = kvp + (size_t)(kb + KBLK) * (2 * HIDDEN);
            nkv = *(const f32x4*)kp;
            nvv = *(const f32x4*)(kp + HIDDEN);
        }

        // ---- K/V fragments from LDS ----
        bf16x8 kfh[4], kfl[4];
        #pragma unroll
        for (int sub = 0; sub < 4; ++sub) {
            kfh[sub] = *(const bf16x8*)(Sb + sub * 512 + (g & 1) * 256 + lr * 16);
            kfl[sub] = *(const bf16x8*)(Sb + 2048 + sub * 512 + (g & 1) * 256 + lr * 16);
        }
        bf16x8 vb0 = *(const bf16x8*)(Sb + 4096 + lr * 128 + ((g * 16) ^ sw));
        bf16x8 vb1 = *(const bf16x8*)(Sb + 4096 + lr * 128 + ((64 + g * 16) ^ sw));

        // ---- QK^T swapped+permuted: s[sub][r] = S[q=lr][key=kb+pi(sub,g,r)] ----
        f32x4 s[4];
        #pragma unroll
        for (int sub = 0; sub < 4; ++sub) {
            f32x4 z = {0.f, 0.f, 0.f, 0.f};
            z = __builtin_amdgcn_mfma_f32_16x16x32_bf16(kfh[sub], qfrag, z, 0, 0, 0);
            s[sub] = __builtin_amdgcn_mfma_f32_16x16x32_bf16(kfl[sub], qfrag, z, 0, 0, 0);
        }
        if (kb + KBLK > kend) {
            #pragma unroll
            for (int sub = 0; sub < 4; ++sub) {
                const int kb2 = kb + (sub >> 1) * 32 + (sub & 1) * 4 + g * 8;
                #pragma unroll
                for (int r = 0; r < 4; ++r)
                    if (kb2 + r >= kend) s[sub][r] = -1e30f;
            }
        }

        // ---- row max: 15 in-lane + 2 shfl ----
        float t0 = fmaxf(fmaxf(s[0][0], s[0][1]), fmaxf(s[0][2], s[0][3]));
        float t1 = fmaxf(fmaxf(s[1][0], s[1][1]), fmaxf(s[1][2], s[1][3]));
        float t2 = fmaxf(fmaxf(s[2][0], s[2][1]), fmaxf(s[2][2], s[2][3]));
        float t3 = fmaxf(fmaxf(s[3][0], s[3][1]), fmaxf(s[3][2], s[3][3]));
        float tmax = fmaxf(fmaxf(t0, t1), fmaxf(t2, t3));
        tmax = fmaxf(tmax, __shfl_xor(tmax, 16));
        tmax = fmaxf(tmax, __shfl_xor(tmax, 32));

        const float mn = fmaxf(m, tmax);
        const float alpha = exp2f(m - mn);
        m = mn;

        // ---- P: in-lane exp2 + pack (C-output IS the PV A-operand) ----
        float rsum = 0.f;
        bf16x8 pa0, pa1;
        #pragma unroll
        for (int sub = 0; sub < 2; ++sub)
            #pragma unroll
            for (int r = 0; r < 4; ++r) {
                float p = exp2f(s[sub][r] - mn);
                rsum += p;
                pa0[sub * 4 + r] = (__bf16)p;
            }
        #pragma unroll
        for (int sub = 2; sub < 4; ++sub)
            #pragma unroll
            for (int r = 0; r < 4; ++r) {
                float p = exp2f(s[sub][r] - mn);
                rsum += p;
                pa1[(sub - 2) * 4 + r] = (__bf16)p;
            }
        rsum += __shfl_xor(rsum, 16);
        rsum += __shfl_xor(rsum, 32);
        lsum = lsum * alpha + rsum;
        acc *= alpha;

        // ---- PV swapped: O^T = V^T * P^T ----
        acc = __builtin_amdgcn_mfma_f32_16x16x32_bf16(vb0, pa0, acc, 0, 0, 0);
        acc = __builtin_amdgcn_mfma_f32_16x16x32_bf16(vb1, pa1, acc, 0, 0, 0);

        // ---- T14 completion: convert + ds_write next tile, then one barrier ----
        if (hasnext)
            cvt_store(&Stg[(ti + 1) & 1][0], ka, vaddr, nkv, nvv);
        __syncthreads();
    }

    // ---- epilogue (m, lsum in base-2 units) ----
    const int qglob = qbase + lr;
    if (SPLIT) {
        const size_t row = (((size_t)b * nc + c0) * S + qglob) * NHEAD + h;
        *(f32x4*)&pbuf[row * DHEAD + g * 4] = acc;
        if (g == 0) { f32x2 ml = {m, lsum}; *(f32x2*)&mlbuf[row * 2] = ml; }
    } else {
        const float inv = 1.0f / lsum;
        *(f32x4*)&out[((size_t)b * S + qglob) * HIDDEN + h * DHEAD + g * 4] = acc * inv;
    }
}

__global__ __launch_bounds__(256)
void mha_merge(const float* __restrict__ pbuf, const float* __restrict__ mlbuf,
               const int* __restrict__ seq_len, float* __restrict__ out, int S, int nc)
{
    const int t = blockIdx.x * 256 + threadIdx.x;   // (b, q, h), h fastest
    const int h = t & (NHEAD - 1);
    const int rest = t >> 3;
    const int qg = rest % S;
    const int b  = rest / S;
    const int L  = seq_len[b];
    const int nch = (L + CHUNK - 1) / CHUNK;

    const size_t cstr = (size_t)S * NHEAD;
    const size_t row0 = ((size_t)b * nc) * cstr + (size_t)qg * NHEAD + h;

    float mv[8], lv[8];
    float M = -1e30f;
    for (int c = 0; c < nch; ++c) {
        f32x2 ml = *(const f32x2*)&mlbuf[(row0 + c * cstr) * 2];
        mv[c] = ml[0]; lv[c] = ml[1];
        M = fmaxf(M, ml[0]);
    }
    float den = 0.f;
    f32x4 o0 = {0,0,0,0}, o1 = o0, o2 = o0, o3 = o0;
    for (int c = 0; c < nch; ++c) {
        float w = exp2f(mv[c] - M);                 // base-2 m
        den += w * lv[c];
        const float* pp = &pbuf[(row0 + c * cstr) * DHEAD];
        o0 += w * *(const f32x4*)&pp[0];
        o1 += w * *(const f32x4*)&pp[4];
        o2 += w * *(const f32x4*)&pp[8];
        o3 += w * *(const f32x4*)&pp[12];
    }
    const float inv = 1.0f / den;
    float* op = &out[((size_t)b * S + qg) * HIDDEN + h * DHEAD];
    *(f32x4*)&op[0]  = o0 * inv;
    *(f32x4*)&op[4]  = o1 * inv;
    *(f32x4*)&op[8]  = o2 * inv;
    *(f32x4*)&op[12] = o3 * inv;
}

extern "C" void kernel_launch(void* const* d_in, const int* in_sizes, int n_in,
                              void* d_out, int out_size, void* d_ws, size_t ws_size,
                              hipStream_t stream)
{
    const float* kv      = (const float*)d_in[0];
    const float* query   = (const float*)d_in[1];
    const int*   seq_len = (const int*)d_in[2];
    float* out           = (float*)d_out;

    const int B = in_sizes[2];
    const int S = in_sizes[1] / (B * HIDDEN);
    const int nc = (S + CHUNK - 1) / CHUNK;

    const size_t pb  = (size_t)B * nc * S * NHEAD * DHEAD * sizeof(float);
    const size_t mlb = (size_t)B * nc * S * NHEAD * 2 * sizeof(float);

    if (nc <= 8 && ws_size >= pb + mlb) {
        float* pbuf  = (float*)d_ws;
        float* mlbuf = (float*)((char*)d_ws + pb);
        mha_fwd<true><<<dim3(S / QBLK, NHEAD, B * nc), dim3(256), 0, stream>>>(
            kv, query, seq_len, nullptr, pbuf, mlbuf, S, nc);
        const int nrows = B * S * NHEAD;
        mha_merge<<<dim3((nrows + 255) / 256), dim3(256), 0, stream>>>(pbuf, mlbuf, seq_len, out, S, nc);
    } else {
        mha_fwd<false><<<dim3(S / QBLK, NHEAD, B), dim3(256), 0, stream>>>(
            kv, query, seq_len, out, nullptr, nullptr, S, 1);
    }
}